// Round 2
// baseline (134.067 us; speedup 1.0000x reference)
//
#include <hip/hip_runtime.h>
#include <hip/hip_bf16.h>

// MiniBatchDiscrimination via bf16 MFMA (gfx950) -- single fused kernel, ZERO
// workspace. x: [32,16,16,256] f32, T: [256,64,8] f32, out: [32,16,16,320] f32.
//
// R2 change: previous best (76.4us) used a pack_T kernel writing B-fragments to
// d_ws; rocprof showed the harness re-poisons the 256MB workspace at ~41us per
// iteration INSIDE the timed region (top-5 dispatches all fillBufferAligned,
// WRITE_SIZE=256MB; neither of our kernels >41us). Dropping d_ws use removes
// that fill from the timed path. Each wave now packs its 16 B-fragments
// directly from T (L2-resident, arithmetic-identical to old pack_T).
//
// Kernel (mbd_main): grid 1024 = (pixel, t-quarter), 256 threads, 4 blocks/CU:
//   pack T-quarter frags from L2 -> stage x to LDS A-frags + passthrough ->
//   MFMA (32/wave) -> park M quarter as f16 -> pairwise exp(-L1) in packed
//   v_pk_*_f16 math -> coalesced o_b stores.

namespace {
constexpr int kN = 32;
constexpr int kHW = 256;
constexpr int kF = 256;          // GEMM K
constexpr int kOutRow = 320;
constexpr int kMstride = 136;    // ushorts/row: 128 + 8 pad (272 B, 16B-aligned)
constexpr int kOstride = 24;     // floats/row in obuf (96 B; 2*24 mod 32 = 16 -> 2-way free)
}

using frag_ab = __attribute__((ext_vector_type(8))) short;   // 8 bf16
using frag_cd = __attribute__((ext_vector_type(4))) float;   // 4 f32
typedef _Float16 h2 __attribute__((ext_vector_type(2)));     // packed f16 pair

__device__ inline unsigned short f2bf(float f) {
  union { __hip_bfloat16 h; unsigned short u; } c;
  c.h = __float2bfloat16(f);
  return c.u;
}

// |a-b| over a packed f16 pair: v_pk_add_f16(neg) + v_and_b32 (clears both signs)
__device__ inline h2 absd2(unsigned a, unsigned b) {
  h2 d = __builtin_bit_cast(h2, a) - __builtin_bit_cast(h2, b);
  return __builtin_bit_cast(h2, __builtin_bit_cast(unsigned, d) & 0x7fff7fffu);
}

// L1 distance over 8 c's held as 4 packed-f16 dwords.
__device__ inline float l1_8(const uint4& a, const uint4& b) {
  h2 s01 = absd2(a.x, b.x) + absd2(a.y, b.y);
  h2 s23 = absd2(a.z, b.z) + absd2(a.w, b.w);
  h2 s = s01 + s23;
  return (float)s.x + (float)s.y;
}

// ---- Fused kernel: T-pack + GEMM + pairwise, one t-quarter per block ----
__global__ __launch_bounds__(256, 4)
void mbd_main(const float* __restrict__ x, const float* __restrict__ T,
              float* __restrict__ out) {
  __shared__ uint4 Afrag[2 * 8 * 64];                           // 16 KB
  __shared__ __align__(16) unsigned short Mlds[kN * kMstride];  // 8.7 KB (f16)
  float* obuf = (float*)Afrag;                                  // [32][24] alias
  const int hw = blockIdx.x & (kHW - 1);
  const int qg = blockIdx.x >> 8;          // t-quarter 0..3 (16 b's, 128 t-cols)
  const int tid = threadIdx.x;
  const int l = tid & 63, w = tid >> 6;    // 4 waves

  // Phase 0: pack this wave's B-fragments straight from T (no workspace).
  // Identical lane mapping to the old pack_T: frag (tT,kt), lane l holds
  // {bf16(T[k0+j][col]), j=0..7} with col = tT*16 + (l&15), k0 = kt*32+(l>>4)*8.
  // T is 512 KB -> L2-resident; each block touches its 128 KB quarter once.
  uint4 bfr[2][8];
  {
    const int colbase = (qg * 8 + w * 2) * 16 + (l & 15);
    const int krow = (l >> 4) * 8;
#pragma unroll
    for (int q = 0; q < 2; ++q) {
      const int col = colbase + q * 16;
#pragma unroll
      for (int kt = 0; kt < 8; ++kt) {
        const int k0 = kt * 32 + krow;
        unsigned p[4];
#pragma unroll
        for (int jj = 0; jj < 4; ++jj) {
          float a = T[(size_t)(k0 + 2 * jj) * 512 + col];
          float b = T[(size_t)(k0 + 2 * jj + 1) * 512 + col];
          p[jj] = (unsigned)f2bf(a) | ((unsigned)f2bf(b) << 16);
        }
        bfr[q][kt] = make_uint4(p[0], p[1], p[2], p[3]);
      }
    }
  }

  // Phase 1: stage x -> A-frags (bf16) + passthrough this quarter's features.
  const float4* x4 = (const float4*)x;
  float4* out4 = (float4*)out;
#pragma unroll
  for (int s = 0; s < 4; ++s) {
    const int task = tid + s * 256;        // 1024 tasks: 32 n x 32 k-groups
    const int n = task >> 5;
    const int k8 = task & 31;              // group of 8 features
    const size_t xb = (size_t)n * (kHW * kF / 4) + (size_t)hw * (kF / 4) + k8 * 2;
    float4 v0 = x4[xb];
    float4 v1 = x4[xb + 1];
    if ((k8 >> 3) == qg) {                 // this block's quarter of features
      const size_t ob = (size_t)(n * kHW + hw) * (kOutRow / 4) + k8 * 2;
      out4[ob] = v0;
      out4[ob + 1] = v1;
    }
    uint4 p;
    p.x = (unsigned)f2bf(v0.x) | ((unsigned)f2bf(v0.y) << 16);
    p.y = (unsigned)f2bf(v0.z) | ((unsigned)f2bf(v0.w) << 16);
    p.z = (unsigned)f2bf(v1.x) | ((unsigned)f2bf(v1.y) << 16);
    p.w = (unsigned)f2bf(v1.z) | ((unsigned)f2bf(v1.w) << 16);
    const int rt = n >> 4, kt = k8 >> 2, ln = (n & 15) | ((k8 & 3) << 4);
    Afrag[(rt * 8 + kt) * 64 + ln] = p;
  }
  __syncthreads();

  // Phase 2: MFMA GEMM; wave w owns t-tiles qg*8 + {2w, 2w+1}.
  frag_cd acc[2][2] = {};                  // [q][rt]
#pragma unroll
  for (int kt = 0; kt < 8; ++kt) {
    uint4 a0 = Afrag[(0 * 8 + kt) * 64 + l];
    uint4 a1 = Afrag[(1 * 8 + kt) * 64 + l];
    frag_ab af0 = __builtin_bit_cast(frag_ab, a0);
    frag_ab af1 = __builtin_bit_cast(frag_ab, a1);
#pragma unroll
    for (int q = 0; q < 2; ++q) {
      frag_ab bf = __builtin_bit_cast(frag_ab, bfr[q][kt]);
      acc[q][0] = __builtin_amdgcn_mfma_f32_16x16x32_bf16(af0, bf, acc[q][0], 0, 0, 0);
      acc[q][1] = __builtin_amdgcn_mfma_f32_16x16x32_bf16(af1, bf, acc[q][1], 0, 0, 0);
    }
  }

  // Phase 3a: park M quarter as f16 (strictly more precise than bf16 parking).
  // C/D: col = l&15, row = (l>>4)*4 + r.
#pragma unroll
  for (int q = 0; q < 2; ++q)
#pragma unroll
    for (int rt = 0; rt < 2; ++rt)
#pragma unroll
      for (int r = 0; r < 4; ++r) {
        const int n = rt * 16 + (l >> 4) * 4 + r;
        const int t = (w * 2 + q) * 16 + (l & 15);  // local col 0..127
        Mlds[n * kMstride + t] =
            __builtin_bit_cast(unsigned short, (_Float16)acc[q][rt][r]);
      }
  __syncthreads();

  // Phase 3b: pairwise exp(-L1), packed f16. Thread: local b = tid>>4 (0..15),
  // i in {i0, i0+1}. A uint4 row-chunk IS 4 packed-f16 c-pairs -> no unpack.
  const int b = tid >> 4;
  const int i0 = (tid & 15) * 2;
  const uint4 mi0 = *(const uint4*)&Mlds[i0 * kMstride + b * 8];
  const uint4 mi1 = *(const uint4*)&Mlds[(i0 + 1) * kMstride + b * 8];
  float ob0 = 0.f, ob1 = 0.f;
#pragma unroll 8
  for (int j = 0; j < kN; ++j) {
    const uint4 mj = *(const uint4*)&Mlds[j * kMstride + b * 8];  // 16-lane bcast
    ob0 += __expf(-l1_8(mi0, mj));
    ob1 += __expf(-l1_8(mi1, mj));
  }
  obuf[i0 * kOstride + b] = ob0;           // aliased over dead Afrag
  obuf[(i0 + 1) * kOstride + b] = ob1;
  __syncthreads();

  // Phase 3c: coalesced o_b stores (32 n x 4 float4 per block).
  if (tid < 128) {
    const int n = tid >> 2;
    const int b4 = tid & 3;
    float4 v = *(const float4*)&obuf[n * kOstride + b4 * 4];
    out4[(size_t)(n * kHW + hw) * (kOutRow / 4) + (kF / 4) + qg * 4 + b4] = v;
  }
}

extern "C" void kernel_launch(void* const* d_in, const int* in_sizes, int n_in,
                              void* d_out, int out_size, void* d_ws, size_t ws_size,
                              hipStream_t stream) {
  const float* x = (const float*)d_in[0];     // [32,16,16,256]
  const float* T = (const float*)d_in[1];     // [256,64,8] = [256][512]
  float* out = (float*)d_out;                 // [32,16,16,320]
  (void)in_sizes; (void)n_in; (void)out_size; (void)d_ws; (void)ws_size;
  mbd_main<<<dim3(4 * kHW), dim3(256), 0, stream>>>(x, T, out);
}

// Round 3
// 75.570 us; speedup vs baseline: 1.7741x; 1.7741x over previous
//
#include <hip/hip_runtime.h>
#include <hip/hip_bf16.h>

// MiniBatchDiscrimination via bf16 MFMA (gfx950).
// x: [32,16,16,256] f32, T: [256,64,8] f32, out: [32,16,16,320] f32.
//
// R3: revert to two-kernel Tf-workspace structure. Evidence from R1/R2
// counters: the harness re-poisons the 256MB workspace EVERY iteration
// regardless of use (R1 fill IDs all ==4 mod 6; R2 cadence 5 with no ws use),
// so d_ws is free. R2's fused T-pack spilled (VGPR=64 vs 64-VGPR bfr array;
// WRITE_SIZE 106MB vs 10.5MB output = scratch traffic) -> mbd 80us. Fix:
//   - B-frags loaded per-kt inside the MFMA loop with +1 prefetch (frees ~48
//     VGPRs; Tf is L2-hot at 256KB).
//   - __launch_bounds__(256,6): 6 blocks/CU (LDS 25KB allows 6.5) for latency
//     hiding + concurrent same-pixel quarters sharing x in L2.
//   - f16 M-parking + packed-f16 pairwise (R1).

namespace {
constexpr int kN = 32;
constexpr int kHW = 256;
constexpr int kF = 256;          // GEMM K
constexpr int kOutRow = 320;
constexpr int kMstride = 136;    // ushorts/row: 128 + 8 pad (272 B, 16B-aligned)
constexpr int kOstride = 24;     // floats/row in obuf (96 B; 2*24 mod 32 = 16 -> 2-way free)
}

using frag_ab = __attribute__((ext_vector_type(8))) short;   // 8 bf16
using frag_cd = __attribute__((ext_vector_type(4))) float;   // 4 f32
typedef _Float16 h2 __attribute__((ext_vector_type(2)));     // packed f16 pair

__device__ inline unsigned short f2bf(float f) {
  union { __hip_bfloat16 h; unsigned short u; } c;
  c.h = __float2bfloat16(f);
  return c.u;
}

// |a-b| over a packed f16 pair: v_pk_add_f16(neg) + v_and_b32 (clears both signs)
__device__ inline h2 absd2(unsigned a, unsigned b) {
  h2 d = __builtin_bit_cast(h2, a) - __builtin_bit_cast(h2, b);
  return __builtin_bit_cast(h2, __builtin_bit_cast(unsigned, d) & 0x7fff7fffu);
}

// L1 distance over 8 c's held as 4 packed-f16 dwords.
__device__ inline float l1_8(const uint4& a, const uint4& b) {
  h2 s01 = absd2(a.x, b.x) + absd2(a.y, b.y);
  h2 s23 = absd2(a.z, b.z) + absd2(a.w, b.w);
  h2 s = s01 + s23;
  return (float)s.x + (float)s.y;
}

// ---- Kernel 1: pack T into MFMA B-fragments (no LDS, no barriers) ----
__global__ __launch_bounds__(256)
void pack_T(const float* __restrict__ T, uint4* __restrict__ Tf) {
  const int g = blockIdx.x * 256 + threadIdx.x;  // 0..16383
  const int l = g & 63;
  const int frag = g >> 6;                       // 0..255 = tt*8 + kt
  const int tt = frag >> 3, kt = frag & 7;
  const int col = tt * 16 + (l & 15);
  const int k0 = kt * 32 + (l >> 4) * 8;
  unsigned p[4];
#pragma unroll
  for (int jj = 0; jj < 4; ++jj) {
    float a = T[(size_t)(k0 + jj * 2) * 512 + col];
    float b = T[(size_t)(k0 + jj * 2 + 1) * 512 + col];
    p[jj] = (unsigned)f2bf(a) | ((unsigned)f2bf(b) << 16);
  }
  Tf[g] = make_uint4(p[0], p[1], p[2], p[3]);
}

// ---- Kernel 2: fused GEMM + pairwise, one t-quarter per block ----
__global__ __launch_bounds__(256, 6)
void mbd_main(const float* __restrict__ x, const uint4* __restrict__ Tf,
              float* __restrict__ out) {
  __shared__ uint4 Afrag[2 * 8 * 64];                           // 16 KB
  __shared__ __align__(16) unsigned short Mlds[kN * kMstride];  // 8.7 KB (f16)
  float* obuf = (float*)Afrag;                                  // [32][24] alias
  const int hw = blockIdx.x & (kHW - 1);
  const int qg = blockIdx.x >> 8;          // t-quarter 0..3 (16 b's, 128 t-cols)
  const int tid = threadIdx.x;
  const int l = tid & 63, w = tid >> 6;    // 4 waves

  // B-frag base for this wave: frag(q,kt) at tf0 + q*512 + kt*64.
  const uint4* tf0 = Tf + (size_t)(qg * 8 + w * 2) * 512 + l;
  // Issue kt=0 loads early so their L2 latency hides under phase 1.
  uint4 bq0 = tf0[0];
  uint4 bq1 = tf0[512];

  // Phase 1: stage x -> A-frags (bf16) + passthrough this quarter's features.
  const float4* x4 = (const float4*)x;
  float4* out4 = (float4*)out;
#pragma unroll
  for (int s = 0; s < 4; ++s) {
    const int task = tid + s * 256;        // 1024 tasks: 32 n x 32 k-groups
    const int n = task >> 5;
    const int k8 = task & 31;              // group of 8 features
    const size_t xb = (size_t)n * (kHW * kF / 4) + (size_t)hw * (kF / 4) + k8 * 2;
    float4 v0 = x4[xb];
    float4 v1 = x4[xb + 1];
    if ((k8 >> 3) == qg) {                 // this block's quarter of features
      const size_t ob = (size_t)(n * kHW + hw) * (kOutRow / 4) + k8 * 2;
      out4[ob] = v0;
      out4[ob + 1] = v1;
    }
    uint4 p;
    p.x = (unsigned)f2bf(v0.x) | ((unsigned)f2bf(v0.y) << 16);
    p.y = (unsigned)f2bf(v0.z) | ((unsigned)f2bf(v0.w) << 16);
    p.z = (unsigned)f2bf(v1.x) | ((unsigned)f2bf(v1.y) << 16);
    p.w = (unsigned)f2bf(v1.z) | ((unsigned)f2bf(v1.w) << 16);
    const int rt = n >> 4, kt = k8 >> 2, ln = (n & 15) | ((k8 & 3) << 4);
    Afrag[(rt * 8 + kt) * 64 + ln] = p;
  }
  __syncthreads();

  // Phase 2: MFMA GEMM; wave w owns t-tiles qg*8 + {2w, 2w+1}.
  // B-frags stream from L2 with +1-kt prefetch (no 64-VGPR resident array).
  frag_cd acc[2][2] = {};                  // [q][rt]
  uint4 nb0, nb1;
#pragma unroll
  for (int kt = 0; kt < 8; ++kt) {
    if (kt < 7) {
      nb0 = tf0[(kt + 1) * 64];
      nb1 = tf0[512 + (kt + 1) * 64];
    }
    uint4 a0 = Afrag[(0 * 8 + kt) * 64 + l];
    uint4 a1 = Afrag[(1 * 8 + kt) * 64 + l];
    frag_ab af0 = __builtin_bit_cast(frag_ab, a0);
    frag_ab af1 = __builtin_bit_cast(frag_ab, a1);
    frag_ab bf0 = __builtin_bit_cast(frag_ab, bq0);
    frag_ab bf1 = __builtin_bit_cast(frag_ab, bq1);
    acc[0][0] = __builtin_amdgcn_mfma_f32_16x16x32_bf16(af0, bf0, acc[0][0], 0, 0, 0);
    acc[0][1] = __builtin_amdgcn_mfma_f32_16x16x32_bf16(af1, bf0, acc[0][1], 0, 0, 0);
    acc[1][0] = __builtin_amdgcn_mfma_f32_16x16x32_bf16(af0, bf1, acc[1][0], 0, 0, 0);
    acc[1][1] = __builtin_amdgcn_mfma_f32_16x16x32_bf16(af1, bf1, acc[1][1], 0, 0, 0);
    bq0 = nb0;
    bq1 = nb1;
  }

  // Phase 3a: park M quarter as f16 (strictly more precise than bf16 parking).
  // C/D: col = l&15, row = (l>>4)*4 + r.
#pragma unroll
  for (int q = 0; q < 2; ++q)
#pragma unroll
    for (int rt = 0; rt < 2; ++rt)
#pragma unroll
      for (int r = 0; r < 4; ++r) {
        const int n = rt * 16 + (l >> 4) * 4 + r;
        const int t = (w * 2 + q) * 16 + (l & 15);  // local col 0..127
        Mlds[n * kMstride + t] =
            __builtin_bit_cast(unsigned short, (_Float16)acc[q][rt][r]);
      }
  __syncthreads();

  // Phase 3b: pairwise exp(-L1), packed f16. Thread: local b = tid>>4 (0..15),
  // i in {i0, i0+1}. A uint4 row-chunk IS 4 packed-f16 c-pairs -> no unpack.
  const int b = tid >> 4;
  const int i0 = (tid & 15) * 2;
  const uint4 mi0 = *(const uint4*)&Mlds[i0 * kMstride + b * 8];
  const uint4 mi1 = *(const uint4*)&Mlds[(i0 + 1) * kMstride + b * 8];
  float ob0 = 0.f, ob1 = 0.f;
#pragma unroll 8
  for (int j = 0; j < kN; ++j) {
    const uint4 mj = *(const uint4*)&Mlds[j * kMstride + b * 8];  // 16-lane bcast
    ob0 += __expf(-l1_8(mi0, mj));
    ob1 += __expf(-l1_8(mi1, mj));
  }
  obuf[i0 * kOstride + b] = ob0;           // aliased over dead Afrag
  obuf[(i0 + 1) * kOstride + b] = ob1;
  __syncthreads();

  // Phase 3c: coalesced o_b stores (32 n x 4 float4 per block).
  if (tid < 128) {
    const int n = tid >> 2;
    const int b4 = tid & 3;
    float4 v = *(const float4*)&obuf[n * kOstride + b4 * 4];
    out4[(size_t)(n * kHW + hw) * (kOutRow / 4) + (kF / 4) + qg * 4 + b4] = v;
  }
}

extern "C" void kernel_launch(void* const* d_in, const int* in_sizes, int n_in,
                              void* d_out, int out_size, void* d_ws, size_t ws_size,
                              hipStream_t stream) {
  const float* x = (const float*)d_in[0];     // [32,16,16,256]
  const float* T = (const float*)d_in[1];     // [256,64,8] = [256][512]
  float* out = (float*)d_out;                 // [32,16,16,320]
  uint4* Tf = (uint4*)d_ws;                   // 256 KB of B-fragments
  (void)in_sizes; (void)n_in; (void)out_size; (void)ws_size;
  pack_T<<<dim3(64), dim3(256), 0, stream>>>(T, Tf);
  mbd_main<<<dim3(4 * kHW), dim3(256), 0, stream>>>(x, Tf, out);
}